// Round 4
// baseline (1319.940 us; speedup 1.0000x reference)
//
#include <hip/hip_runtime.h>

#define NN 100000
#define EE 800000
#define HH 128
#define LL 4
#define GG 64
#define BN_EPS 1e-5f
#define LN_EPS 1e-5f
#define POOL_CHUNK 64
#define NBUK ((NN + 255) >> 8)   // 391 buckets of 256 rows
#define CAP 8192
#define BCHUNK 8192

typedef __attribute__((ext_vector_type(8))) short short8;
typedef __attribute__((ext_vector_type(4))) float f32x4;

__device__ inline unsigned short bf16_rne(float f) {
    unsigned u = __float_as_uint(f);
    return (unsigned short)((u + 0x7FFF + ((u >> 16) & 1)) >> 16);
}
__device__ inline float bf16_to_f32(unsigned short h) {
    return __uint_as_float((unsigned)h << 16);
}

// ---------------- CSR build: bucket sort (256 rows / bucket) ----------------

__global__ __launch_bounds__(256) void bucket_count(const int* __restrict__ ei, int* __restrict__ bcnt) {
    __shared__ int h[NBUK];
    int tid = threadIdx.x;
    for (int i = tid; i < NBUK; i += 256) h[i] = 0;
    __syncthreads();
    for (int e = blockIdx.x * 256 + tid; e < 2 * EE; e += gridDim.x * 256) {
        int r = ei[e];
        int c = (e < EE) ? ei[e + EE] : ei[e - EE];
        if (r != c) atomicAdd(&h[r >> 8], 1);
    }
    __syncthreads();
    for (int i = tid; i < NBUK; i += 256) if (h[i]) atomicAdd(&bcnt[i], h[i]);
}

__global__ void bucket_scan(const int* __restrict__ bcnt, int* __restrict__ bbase,
                            int* __restrict__ bcur, int* __restrict__ rp) {
    __shared__ int sh[512];
    int t = threadIdx.x;
    sh[t] = (t < NBUK) ? bcnt[t] : 0;
    __syncthreads();
    for (int off = 1; off < 512; off <<= 1) {
        int x = (t >= off) ? sh[t - off] : 0;
        __syncthreads();
        sh[t] += x;
        __syncthreads();
    }
    if (t < NBUK) {
        int excl = (t > 0) ? sh[t - 1] : 0;
        bbase[t] = excl;
        bcur[t] = excl;
    }
    if (t == NBUK - 1) {
        bbase[NBUK] = sh[t];
        rp[NN] = sh[t];
    }
}

__global__ __launch_bounds__(256) void bucket_scatter(const int* __restrict__ ei, int* __restrict__ bcur,
                                                      int* __restrict__ pairs) {
    __shared__ int h[NBUK];
    __shared__ int curb[NBUK];
    int tid = threadIdx.x;
    for (int i = tid; i < NBUK; i += 256) h[i] = 0;
    __syncthreads();
    int base = blockIdx.x * BCHUNK;
#pragma unroll 4
    for (int k = 0; k < BCHUNK / 256; k++) {
        int e = base + k * 256 + tid;
        if (e < 2 * EE) {
            int r = ei[e];
            int c = (e < EE) ? ei[e + EE] : ei[e - EE];
            if (r != c) atomicAdd(&h[r >> 8], 1);
        }
    }
    __syncthreads();
    for (int i = tid; i < NBUK; i += 256) {
        int n = h[i];
        curb[i] = n ? atomicAdd(&bcur[i], n) : 0;
    }
    __syncthreads();
#pragma unroll 4
    for (int k = 0; k < BCHUNK / 256; k++) {
        int e = base + k * 256 + tid;
        if (e < 2 * EE) {
            int r = ei[e];
            int c = (e < EE) ? ei[e + EE] : ei[e - EE];
            if (r != c) {
                int p = atomicAdd(&curb[r >> 8], 1);
                pairs[p] = ((r & 255) << 17) | c;
            }
        }
    }
}

__global__ __launch_bounds__(256) void bucket_build(const int* __restrict__ pairs, const int* __restrict__ bbase,
                                                    int* __restrict__ rp, int* __restrict__ colidx) {
    __shared__ int hist[256], off[256], lcol[CAP];
    int b = blockIdx.x, tid = threadIdx.x;
    int s = bbase[b];
    int size = bbase[b + 1] - s;
    hist[tid] = 0;
    __syncthreads();
    for (int i = tid; i < size; i += 256) atomicAdd(&hist[pairs[s + i] >> 17], 1);
    __syncthreads();
    off[tid] = hist[tid];
    __syncthreads();
    for (int o = 1; o < 256; o <<= 1) {
        int x = (tid >= o) ? off[tid - o] : 0;
        __syncthreads();
        off[tid] += x;
        __syncthreads();
    }
    int excl = (tid > 0) ? off[tid - 1] : 0;
    int r = (b << 8) + tid;
    if (r < NN) rp[r] = s + excl;
    hist[tid] = excl;
    __syncthreads();
    if (size <= CAP) {
        for (int i = tid; i < size; i += 256) {
            int u = pairs[s + i];
            int p = atomicAdd(&hist[u >> 17], 1);
            lcol[p] = u & 0x1FFFF;
        }
        __syncthreads();
        for (int i = tid; i < size; i += 256) colidx[s + i] = lcol[i];
    } else {
        for (int i = tid; i < size; i += 256) {
            int u = pairs[s + i];
            int p = atomicAdd(&hist[u >> 17], 1);
            colidx[s + p] = u & 0x1FFFF;
        }
    }
}

// ---------------- weight prep: transpose + split fp32 -> bf16 hi/lo ----------------

__global__ void prep_w(const float* __restrict__ W0, const float* __restrict__ W1,
                       const float* __restrict__ W2,
                       short* __restrict__ wt_hi, short* __restrict__ wt_lo) {
    int i = blockIdx.x * 256 + threadIdx.x;
    if (i >= 9 * HH * HH) return;
    int mat = i >> 14, rem = i & 16383;
    int n = rem >> 7, k = rem & 127;
    const float* src = (mat == 0) ? W0 : ((mat <= 4) ? W1 + (size_t)(mat - 1) * HH * HH
                                                     : W2 + (size_t)(mat - 5) * HH * HH);
    float v = src[(size_t)k * HH + n];
    unsigned short h = bf16_rne(v);
    wt_hi[i] = (short)h;
    wt_lo[i] = (short)bf16_rne(v - bf16_to_f32(h));
}

// ---------------- fused GEMM, 64 rows/block, wave = 16 rows ----------------
// MODE 0: Out(hbuf) = x @ W0 + b0; also hbf
// MODE 1: Out(z1) = u @ W1 + b1 where u = (1+eps)h + sum_nb h (gathered from hbf); col stats
// MODE 2: A' = relu(BN(z1)); Hbuf = LN(Hbuf + relu(A'@W2 + b2)); also hbf

template<int MODE>
__global__ __launch_bounds__(256) void fused_gemm(
    const float* __restrict__ A, const unsigned* __restrict__ hbf_u,
    const int* __restrict__ rp, const int* __restrict__ colidx,
    const float* __restrict__ eps_l, int layer,
    const short* __restrict__ wt_hi, const short* __restrict__ wt_lo,
    const float* __restrict__ bias,
    float* __restrict__ Out,
    float* __restrict__ colsum, float* __restrict__ colsq,
    const float* __restrict__ bng, const float* __restrict__ bnb,
    const float* __restrict__ lng, const float* __restrict__ lnb,
    float* __restrict__ Hbuf, unsigned short* __restrict__ hbf_out)
{
    __shared__ float uls[64][132];
    __shared__ float csum[HH], csq[HH];
    __shared__ float bsc[HH], bsh[HH];
    int tid = threadIdx.x;
    int wave = tid >> 6, lane = tid & 63;
    int r0 = blockIdx.x * 64;
    int rw = r0 + wave * 16;

    if (MODE == 1 && tid < HH) { csum[tid] = 0.f; csq[tid] = 0.f; }
    if (MODE == 2 && tid < HH) {
        float m = colsum[tid] * (1.f / NN);
        float v = colsq[tid] * (1.f / NN) - m * m;
        float a = bng[tid] * rsqrtf(v + BN_EPS);
        bsc[tid] = a;
        bsh[tid] = bnb[tid] - m * a;
    }
    if (MODE == 2) __syncthreads();

    // ---- stage A-tile (64 rows x 128) into LDS ----
    if (MODE == 1) {
        float eps1 = 1.0f + eps_l[layer];
        for (int rl = 0; rl < 16; rl++) {
            int r = rw + rl;
            float ax = 0.f, ay = 0.f;
            if (r < NN) {
                unsigned sv = hbf_u[r * 64 + lane];
                ax = __uint_as_float(sv << 16) * eps1;
                ay = __uint_as_float(sv & 0xFFFF0000u) * eps1;
                int i = rp[r], end = rp[r + 1];
                for (; i + 4 <= end; i += 4) {
                    unsigned v0 = hbf_u[colidx[i] * 64 + lane];
                    unsigned v1 = hbf_u[colidx[i + 1] * 64 + lane];
                    unsigned v2 = hbf_u[colidx[i + 2] * 64 + lane];
                    unsigned v3 = hbf_u[colidx[i + 3] * 64 + lane];
                    ax += __uint_as_float(v0 << 16) + __uint_as_float(v1 << 16)
                        + __uint_as_float(v2 << 16) + __uint_as_float(v3 << 16);
                    ay += __uint_as_float(v0 & 0xFFFF0000u) + __uint_as_float(v1 & 0xFFFF0000u)
                        + __uint_as_float(v2 & 0xFFFF0000u) + __uint_as_float(v3 & 0xFFFF0000u);
                }
                for (; i < end; i++) {
                    unsigned v = hbf_u[colidx[i] * 64 + lane];
                    ax += __uint_as_float(v << 16);
                    ay += __uint_as_float(v & 0xFFFF0000u);
                }
            }
            *(float2*)&uls[wave * 16 + rl][2 * lane] = make_float2(ax, ay);
        }
    } else {
#pragma unroll
        for (int p = 0; p < 8; p++) {
            int i = p * 256 + tid;
            int row = i >> 5, c4 = (i & 31) << 2;
            int r = r0 + row;
            float4 v = (r < NN) ? *(const float4*)(A + (size_t)r * HH + c4)
                                : make_float4(0.f, 0.f, 0.f, 0.f);
            if (MODE == 2) {
                v.x = fmaxf(fmaf(v.x, bsc[c4 + 0], bsh[c4 + 0]), 0.f);
                v.y = fmaxf(fmaf(v.y, bsc[c4 + 1], bsh[c4 + 1]), 0.f);
                v.z = fmaxf(fmaf(v.z, bsc[c4 + 2], bsh[c4 + 2]), 0.f);
                v.w = fmaxf(fmaf(v.w, bsc[c4 + 3], bsh[c4 + 3]), 0.f);
            }
            *(float4*)&uls[row][c4] = v;
        }
    }
    __syncthreads();

    // ---- MFMA: 16 rows x 128 cols per wave ----
    int lrow = lane & 15, kgrp = lane >> 4;
    f32x4 acc[8];
#pragma unroll
    for (int c = 0; c < 8; c++) acc[c] = (f32x4){0.f, 0.f, 0.f, 0.f};

#pragma unroll
    for (int ks = 0; ks < 4; ks++) {
        int kb = ks * 32 + kgrp * 8;
        float4 p0 = *(const float4*)&uls[wave * 16 + lrow][kb];
        float4 p1 = *(const float4*)&uls[wave * 16 + lrow][kb + 4];
        float av[8] = {p0.x, p0.y, p0.z, p0.w, p1.x, p1.y, p1.z, p1.w};
        short8 ahi, alo;
#pragma unroll
        for (int j = 0; j < 8; j++) {
            unsigned short hb = bf16_rne(av[j]);
            ahi[j] = (short)hb;
            alo[j] = (short)bf16_rne(av[j] - bf16_to_f32(hb));
        }
#pragma unroll
        for (int c = 0; c < 8; c++) {
            size_t woff = (size_t)(c * 16 + lrow) * HH + kb;
            short8 whi = *(const short8*)(wt_hi + woff);
            short8 wlo = *(const short8*)(wt_lo + woff);
            acc[c] = __builtin_amdgcn_mfma_f32_16x16x32_bf16(ahi, whi, acc[c], 0, 0, 0);
            acc[c] = __builtin_amdgcn_mfma_f32_16x16x32_bf16(alo, whi, acc[c], 0, 0, 0);
            acc[c] = __builtin_amdgcn_mfma_f32_16x16x32_bf16(ahi, wlo, acc[c], 0, 0, 0);
        }
    }
    __syncthreads();

    // ---- stage z = acc + bias back to LDS (C layout: row=kgrp*4+reg, col=c*16+lrow) ----
#pragma unroll
    for (int c = 0; c < 8; c++) {
        float bv = bias[c * 16 + lrow];
#pragma unroll
        for (int reg = 0; reg < 4; reg++)
            uls[wave * 16 + kgrp * 4 + reg][c * 16 + lrow] = acc[c][reg] + bv;
    }
    __syncthreads();

    // ---- row-major epilogue: lane (r4, c16) handles 8 cols of 4 rows/pass ----
    int r4 = lane >> 4, c16 = lane & 15;
    float ps[8], pq[8];
    if (MODE == 1) {
#pragma unroll
        for (int j = 0; j < 8; j++) { ps[j] = 0.f; pq[j] = 0.f; }
    }
    float lg[8], lb[8];
    if (MODE == 2) {
        float4 g0 = *(const float4*)(lng + c16 * 8);
        float4 g1 = *(const float4*)(lng + c16 * 8 + 4);
        float4 b0v = *(const float4*)(lnb + c16 * 8);
        float4 b1v = *(const float4*)(lnb + c16 * 8 + 4);
        lg[0] = g0.x; lg[1] = g0.y; lg[2] = g0.z; lg[3] = g0.w;
        lg[4] = g1.x; lg[5] = g1.y; lg[6] = g1.z; lg[7] = g1.w;
        lb[0] = b0v.x; lb[1] = b0v.y; lb[2] = b0v.z; lb[3] = b0v.w;
        lb[4] = b1v.x; lb[5] = b1v.y; lb[6] = b1v.z; lb[7] = b1v.w;
    }

#pragma unroll
    for (int pass = 0; pass < 4; pass++) {
        int rl = pass * 4 + r4;
        int r = rw + rl;
        float4 z0 = *(const float4*)&uls[wave * 16 + rl][c16 * 8];
        float4 z1v = *(const float4*)&uls[wave * 16 + rl][c16 * 8 + 4];
        float z[8] = {z0.x, z0.y, z0.z, z0.w, z1v.x, z1v.y, z1v.z, z1v.w};
        if (MODE == 0) {
            if (r < NN) {
                float4* o = (float4*)(Out + (size_t)r * HH + c16 * 8);
                o[0] = make_float4(z[0], z[1], z[2], z[3]);
                o[1] = make_float4(z[4], z[5], z[6], z[7]);
                uint4 pk;
                pk.x = (unsigned)bf16_rne(z[0]) | ((unsigned)bf16_rne(z[1]) << 16);
                pk.y = (unsigned)bf16_rne(z[2]) | ((unsigned)bf16_rne(z[3]) << 16);
                pk.z = (unsigned)bf16_rne(z[4]) | ((unsigned)bf16_rne(z[5]) << 16);
                pk.w = (unsigned)bf16_rne(z[6]) | ((unsigned)bf16_rne(z[7]) << 16);
                *(uint4*)(hbf_out + (size_t)r * HH + c16 * 8) = pk;
            }
        } else if (MODE == 1) {
            if (r < NN) {
                float4* o = (float4*)(Out + (size_t)r * HH + c16 * 8);
                o[0] = make_float4(z[0], z[1], z[2], z[3]);
                o[1] = make_float4(z[4], z[5], z[6], z[7]);
#pragma unroll
                for (int j = 0; j < 8; j++) { ps[j] += z[j]; pq[j] += z[j] * z[j]; }
            }
        } else {
            float t[8];
            if (r < NN) {
                float4 h0 = *(const float4*)(Hbuf + (size_t)r * HH + c16 * 8);
                float4 h1 = *(const float4*)(Hbuf + (size_t)r * HH + c16 * 8 + 4);
                float hv[8] = {h0.x, h0.y, h0.z, h0.w, h1.x, h1.y, h1.z, h1.w};
                float s = 0.f, q = 0.f;
#pragma unroll
                for (int j = 0; j < 8; j++) {
                    t[j] = hv[j] + fmaxf(z[j], 0.f);
                    s += t[j]; q += t[j] * t[j];
                }
#pragma unroll
                for (int m = 1; m < 16; m <<= 1) {
                    s += __shfl_xor(s, m, 16);
                    q += __shfl_xor(q, m, 16);
                }
                float mu = s * (1.f / 128.f);
                float var = q * (1.f / 128.f) - mu * mu;
                float rs = rsqrtf(var + LN_EPS);
                float o[8];
#pragma unroll
                for (int j = 0; j < 8; j++) o[j] = (t[j] - mu) * rs * lg[j] + lb[j];
                float4* op = (float4*)(Hbuf + (size_t)r * HH + c16 * 8);
                op[0] = make_float4(o[0], o[1], o[2], o[3]);
                op[1] = make_float4(o[4], o[5], o[6], o[7]);
                uint4 pk;
                pk.x = (unsigned)bf16_rne(o[0]) | ((unsigned)bf16_rne(o[1]) << 16);
                pk.y = (unsigned)bf16_rne(o[2]) | ((unsigned)bf16_rne(o[3]) << 16);
                pk.z = (unsigned)bf16_rne(o[4]) | ((unsigned)bf16_rne(o[5]) << 16);
                pk.w = (unsigned)bf16_rne(o[6]) | ((unsigned)bf16_rne(o[7]) << 16);
                *(uint4*)(hbf_out + (size_t)r * HH + c16 * 8) = pk;
            } else {
                // keep shfl participation uniform within the 16-lane group:
                float s = 0.f, q = 0.f;
#pragma unroll
                for (int m = 1; m < 16; m <<= 1) { s += __shfl_xor(s, m, 16); q += __shfl_xor(q, m, 16); }
            }
        }
    }

    if (MODE == 1) {
        // reduce across the 4 lanes (r4) sharing c16
#pragma unroll
        for (int j = 0; j < 8; j++) {
            ps[j] += __shfl_xor(ps[j], 16);
            ps[j] += __shfl_xor(ps[j], 32);
            pq[j] += __shfl_xor(pq[j], 16);
            pq[j] += __shfl_xor(pq[j], 32);
        }
        if (r4 == 0) {
#pragma unroll
            for (int j = 0; j < 8; j++) {
                atomicAdd(&csum[c16 * 8 + j], ps[j]);
                atomicAdd(&csq[c16 * 8 + j], pq[j]);
            }
        }
        __syncthreads();
        if (tid < HH) {
            atomicAdd(&colsum[tid], csum[tid]);
            atomicAdd(&colsq[tid], csq[tid]);
        }
    }
}

// ---------------- pooling ----------------

__global__ void pool_kernel(const float* __restrict__ h, const int* __restrict__ batch,
                            float* __restrict__ psum, float* __restrict__ pcnt)
{
    int t = threadIdx.x;  // 128
    int n0 = blockIdx.x * POOL_CHUNK;
    int n1 = n0 + POOL_CHUNK; if (n1 > NN) n1 = NN;
    if (n0 >= NN) return;
    float acc = 0.f;
    int cur = batch[n0];
    int cnt = 0;
    for (int n = n0; n < n1; n++) {
        int g = batch[n];
        if (g != cur) {
            atomicAdd(&psum[cur * HH + t], acc);
            if (t == 0) atomicAdd(&pcnt[cur], (float)cnt);
            acc = 0.f; cnt = 0; cur = g;
        }
        acc += h[(size_t)n * HH + t];
        cnt++;
    }
    atomicAdd(&psum[cur * HH + t], acc);
    if (t == 0) atomicAdd(&pcnt[cur], (float)cnt);
}

__global__ void pool_final(const float* __restrict__ psum, const float* __restrict__ pcnt,
                           float* __restrict__ out)
{
    int i = blockIdx.x * blockDim.x + threadIdx.x;
    if (i < GG * HH) {
        float c = pcnt[i >> 7];
        out[i] = psum[i] / fmaxf(c, 1.f);
    }
}

// ---------------- launch ----------------

extern "C" void kernel_launch(void* const* d_in, const int* in_sizes, int n_in,
                              void* d_out, int out_size, void* d_ws, size_t ws_size,
                              hipStream_t stream)
{
    const float* x     = (const float*)d_in[0];
    const float* W0    = (const float*)d_in[1];
    const float* b0    = (const float*)d_in[2];
    const float* eps_l = (const float*)d_in[3];
    const float* W1    = (const float*)d_in[4];
    const float* b1    = (const float*)d_in[5];
    const float* bng   = (const float*)d_in[6];
    const float* bnb   = (const float*)d_in[7];
    const float* W2    = (const float*)d_in[8];
    const float* b2    = (const float*)d_in[9];
    const float* lng   = (const float*)d_in[10];
    const float* lnb   = (const float*)d_in[11];
    const int*   ei    = (const int*)d_in[12];
    const int*   batch = (const int*)d_in[13];
    float* out = (float*)d_out;

    char* ws = (char*)d_ws;
    size_t off = 0;
    auto alloc = [&](size_t bytes) -> void* {
        void* p = ws + off;
        off += (bytes + 255) & ~(size_t)255;
        return p;
    };
    float* hbuf   = (float*)alloc((size_t)NN * HH * 4);
    float* ubuf   = (float*)alloc((size_t)NN * HH * 4);   // z1
    unsigned short* hbf = (unsigned short*)alloc((size_t)NN * HH * 2);
    int*   colidx = (int*)alloc((size_t)2 * EE * 4);
    int*   pairs  = (int*)alloc((size_t)2 * EE * 4);
    int*   rp     = (int*)alloc((size_t)(NN + 1) * 4);
    int*   bcnt   = (int*)alloc((NBUK + 1) * 4);
    int*   bbase  = (int*)alloc((NBUK + 1) * 4);
    int*   bcur   = (int*)alloc((NBUK + 1) * 4);
    float* colsum = (float*)alloc((size_t)LL * HH * 2 * 4);  // [l][2][HH]
    float* psum   = (float*)alloc((size_t)GG * HH * 4);
    float* pcnt   = (float*)alloc(GG * 4);
    short* wt_hi  = (short*)alloc((size_t)9 * HH * HH * 2);
    short* wt_lo  = (short*)alloc((size_t)9 * HH * HH * 2);

    hipMemsetAsync(bcnt, 0, (NBUK + 1) * 4, stream);
    hipMemsetAsync(colsum, 0, (size_t)LL * HH * 2 * 4, stream);
    hipMemsetAsync(psum, 0, (size_t)GG * HH * 4, stream);
    hipMemsetAsync(pcnt, 0, GG * 4, stream);

    prep_w<<<(9 * HH * HH + 255) / 256, 256, 0, stream>>>(W0, W1, W2, wt_hi, wt_lo);

    bucket_count<<<512, 256, 0, stream>>>(ei, bcnt);
    bucket_scan<<<1, 512, 0, stream>>>(bcnt, bbase, bcur, rp);
    bucket_scatter<<<(2 * EE + BCHUNK - 1) / BCHUNK, 256, 0, stream>>>(ei, bcur, pairs);
    bucket_build<<<NBUK, 256, 0, stream>>>(pairs, bbase, rp, colidx);

    int gb = (NN + 63) / 64;
    // encode: hbuf = x @ W0 + b0 (+ hbf mirror)
    fused_gemm<0><<<gb, 256, 0, stream>>>(x, nullptr, nullptr, nullptr, nullptr, 0,
                                          wt_hi, wt_lo, b0, hbuf,
                                          nullptr, nullptr, nullptr, nullptr, nullptr, nullptr,
                                          nullptr, hbf);

    for (int l = 0; l < LL; l++) {
        float* cs = colsum + (size_t)l * HH * 2;
        float* cq = cs + HH;
        // z1 = ((1+eps)h + sum_nb h) @ W1 + b1, col stats
        fused_gemm<1><<<gb, 256, 0, stream>>>(nullptr, (const unsigned*)hbf, rp, colidx, eps_l, l,
                                              wt_hi + (size_t)(1 + l) * HH * HH,
                                              wt_lo + (size_t)(1 + l) * HH * HH, b1 + l * HH, ubuf,
                                              cs, cq, nullptr, nullptr, nullptr, nullptr,
                                              nullptr, nullptr);
        // h = LN(h + relu(relu(BN(z1)) @ W2 + b2)) (+ hbf mirror)
        fused_gemm<2><<<gb, 256, 0, stream>>>(ubuf, nullptr, nullptr, nullptr, nullptr, 0,
                                              wt_hi + (size_t)(5 + l) * HH * HH,
                                              wt_lo + (size_t)(5 + l) * HH * HH, b2 + l * HH, nullptr,
                                              cs, cq, bng + l * HH, bnb + l * HH,
                                              lng + l * HH, lnb + l * HH, hbuf, hbf);
    }

    pool_kernel<<<(NN + POOL_CHUNK - 1) / POOL_CHUNK, 128, 0, stream>>>(hbuf, batch, psum, pcnt);
    pool_final<<<(GG * HH + 255) / 256, 256, 0, stream>>>(psum, pcnt, out);
}

// Round 5
// 1202.315 us; speedup vs baseline: 1.0978x; 1.0978x over previous
//
#include <hip/hip_runtime.h>

#define NN 100000
#define EE 800000
#define HH 128
#define LL 4
#define GG 64
#define BN_EPS 1e-5f
#define LN_EPS 1e-5f
#define POOL_CHUNK 64
#define NBUK ((NN + 255) >> 8)   // 391 buckets of 256 rows
#define CAP 8192
#define BCHUNK 8192

typedef __attribute__((ext_vector_type(8))) short short8;
typedef __attribute__((ext_vector_type(4))) float f32x4;

__device__ inline unsigned short bf16_rne(float f) {
    unsigned u = __float_as_uint(f);
    return (unsigned short)((u + 0x7FFF + ((u >> 16) & 1)) >> 16);
}
__device__ inline float bf16_to_f32(unsigned short h) {
    return __uint_as_float((unsigned)h << 16);
}

// ---------------- CSR build: bucket sort (256 rows / bucket) ----------------

__global__ __launch_bounds__(256) void bucket_count(const int* __restrict__ ei, int* __restrict__ bcnt) {
    __shared__ int h[NBUK];
    int tid = threadIdx.x;
    for (int i = tid; i < NBUK; i += 256) h[i] = 0;
    __syncthreads();
    for (int e = blockIdx.x * 256 + tid; e < 2 * EE; e += gridDim.x * 256) {
        int r = ei[e];
        int c = (e < EE) ? ei[e + EE] : ei[e - EE];
        if (r != c) atomicAdd(&h[r >> 8], 1);
    }
    __syncthreads();
    for (int i = tid; i < NBUK; i += 256) if (h[i]) atomicAdd(&bcnt[i], h[i]);
}

__global__ void bucket_scan(const int* __restrict__ bcnt, int* __restrict__ bbase,
                            int* __restrict__ bcur, int* __restrict__ rp) {
    __shared__ int sh[512];
    int t = threadIdx.x;
    sh[t] = (t < NBUK) ? bcnt[t] : 0;
    __syncthreads();
    for (int off = 1; off < 512; off <<= 1) {
        int x = (t >= off) ? sh[t - off] : 0;
        __syncthreads();
        sh[t] += x;
        __syncthreads();
    }
    if (t < NBUK) {
        int excl = (t > 0) ? sh[t - 1] : 0;
        bbase[t] = excl;
        bcur[t] = excl;
    }
    if (t == NBUK - 1) {
        bbase[NBUK] = sh[t];
        rp[NN] = sh[t];
    }
}

__global__ __launch_bounds__(256) void bucket_scatter(const int* __restrict__ ei, int* __restrict__ bcur,
                                                      int* __restrict__ pairs) {
    __shared__ int h[NBUK];
    __shared__ int curb[NBUK];
    int tid = threadIdx.x;
    for (int i = tid; i < NBUK; i += 256) h[i] = 0;
    __syncthreads();
    int base = blockIdx.x * BCHUNK;
#pragma unroll 4
    for (int k = 0; k < BCHUNK / 256; k++) {
        int e = base + k * 256 + tid;
        if (e < 2 * EE) {
            int r = ei[e];
            int c = (e < EE) ? ei[e + EE] : ei[e - EE];
            if (r != c) atomicAdd(&h[r >> 8], 1);
        }
    }
    __syncthreads();
    for (int i = tid; i < NBUK; i += 256) {
        int n = h[i];
        curb[i] = n ? atomicAdd(&bcur[i], n) : 0;
    }
    __syncthreads();
#pragma unroll 4
    for (int k = 0; k < BCHUNK / 256; k++) {
        int e = base + k * 256 + tid;
        if (e < 2 * EE) {
            int r = ei[e];
            int c = (e < EE) ? ei[e + EE] : ei[e - EE];
            if (r != c) {
                int p = atomicAdd(&curb[r >> 8], 1);
                pairs[p] = ((r & 255) << 17) | c;
            }
        }
    }
}

__global__ __launch_bounds__(256) void bucket_build(const int* __restrict__ pairs, const int* __restrict__ bbase,
                                                    int* __restrict__ rp, int* __restrict__ colidx) {
    __shared__ int hist[256], off[256], lcol[CAP];
    int b = blockIdx.x, tid = threadIdx.x;
    int s = bbase[b];
    int size = bbase[b + 1] - s;
    hist[tid] = 0;
    __syncthreads();
    for (int i = tid; i < size; i += 256) atomicAdd(&hist[pairs[s + i] >> 17], 1);
    __syncthreads();
    off[tid] = hist[tid];
    __syncthreads();
    for (int o = 1; o < 256; o <<= 1) {
        int x = (tid >= o) ? off[tid - o] : 0;
        __syncthreads();
        off[tid] += x;
        __syncthreads();
    }
    int excl = (tid > 0) ? off[tid - 1] : 0;
    int r = (b << 8) + tid;
    if (r < NN) rp[r] = s + excl;
    hist[tid] = excl;
    __syncthreads();
    if (size <= CAP) {
        for (int i = tid; i < size; i += 256) {
            int u = pairs[s + i];
            int p = atomicAdd(&hist[u >> 17], 1);
            lcol[p] = u & 0x1FFFF;
        }
        __syncthreads();
        for (int i = tid; i < size; i += 256) colidx[s + i] = lcol[i];
    } else {
        for (int i = tid; i < size; i += 256) {
            int u = pairs[s + i];
            int p = atomicAdd(&hist[u >> 17], 1);
            colidx[s + p] = u & 0x1FFFF;
        }
    }
}

// ---------------- weight prep: transpose + split fp32 -> bf16 hi/lo ----------------

__global__ void prep_w(const float* __restrict__ W0, const float* __restrict__ W1,
                       const float* __restrict__ W2,
                       short* __restrict__ wt_hi, short* __restrict__ wt_lo) {
    int i = blockIdx.x * 256 + threadIdx.x;
    if (i >= 9 * HH * HH) return;
    int mat = i >> 14, rem = i & 16383;
    int n = rem >> 7, k = rem & 127;
    const float* src = (mat == 0) ? W0 : ((mat <= 4) ? W1 + (size_t)(mat - 1) * HH * HH
                                                     : W2 + (size_t)(mat - 5) * HH * HH);
    float v = src[(size_t)k * HH + n];
    unsigned short h = bf16_rne(v);
    wt_hi[i] = (short)h;
    wt_lo[i] = (short)bf16_rne(v - bf16_to_f32(h));
}

// ---------------- aggregation: u = (1+eps)*h + sum_nb h[nb], gather from bf16 mirror ----------------
// one node per wave: max TLP for latency hiding

__global__ __launch_bounds__(256) void agg_kernel(
    const unsigned int* __restrict__ hbf, const int* __restrict__ rp, const int* __restrict__ colidx,
    const float* __restrict__ eps_l, int layer, float* __restrict__ u)
{
    int node = blockIdx.x * 4 + (threadIdx.x >> 6);
    if (node >= NN) return;
    int lane = threadIdx.x & 63;
    float eps1 = 1.0f + eps_l[layer];
    unsigned sv = hbf[node * 64 + lane];
    float ax = __uint_as_float(sv << 16) * eps1;
    float ay = __uint_as_float(sv & 0xFFFF0000u) * eps1;
    int i = rp[node], end = rp[node + 1];
    for (; i + 4 <= end; i += 4) {
        unsigned v0 = hbf[colidx[i] * 64 + lane];
        unsigned v1 = hbf[colidx[i + 1] * 64 + lane];
        unsigned v2 = hbf[colidx[i + 2] * 64 + lane];
        unsigned v3 = hbf[colidx[i + 3] * 64 + lane];
        ax += __uint_as_float(v0 << 16) + __uint_as_float(v1 << 16)
            + __uint_as_float(v2 << 16) + __uint_as_float(v3 << 16);
        ay += __uint_as_float(v0 & 0xFFFF0000u) + __uint_as_float(v1 & 0xFFFF0000u)
            + __uint_as_float(v2 & 0xFFFF0000u) + __uint_as_float(v3 & 0xFFFF0000u);
    }
    for (; i < end; i++) {
        unsigned v = hbf[colidx[i] * 64 + lane];
        ax += __uint_as_float(v << 16);
        ay += __uint_as_float(v & 0xFFFF0000u);
    }
    ((float2*)(u + (size_t)node * HH))[lane] = make_float2(ax, ay);
}

// ---------------- GEMM v5: 64 rows/block (wave=16 rows), split-bf16 MFMA ----------------
// Direct global A-frag loads; LDS only for C staging (two 32-row passes -> 19 KB).
// MODE 0: Out = A@W + bias; + hbf mirror
// MODE 1: Out = A@W + bias (in-place safe); column stats -> colsum/colsq
// MODE 2: A' = relu(BN(A)); Hbuf = LN(Hbuf + relu(A'@W + bias)); + hbf mirror (if non-null)

template<int MODE>
__global__ __launch_bounds__(256) void gemm_v5(
    const float* __restrict__ A,
    const short* __restrict__ wt_hi, const short* __restrict__ wt_lo,
    const float* __restrict__ bias,
    float* __restrict__ Out,
    float* __restrict__ colsum, float* __restrict__ colsq,
    const float* __restrict__ bng, const float* __restrict__ bnb,
    const float* __restrict__ lng, const float* __restrict__ lnb,
    float* __restrict__ Hbuf, unsigned short* __restrict__ hbf_out)
{
    __shared__ float cstage[32][132];
    __shared__ float csum[HH], csq[HH];
    __shared__ float bsc[HH], bsh[HH];
    int tid = threadIdx.x;
    int wave = tid >> 6, lane = tid & 63;
    int lrow = lane & 15, kgrp = lane >> 4;
    int r0 = blockIdx.x * 64;

    if (MODE == 1 && tid < HH) { csum[tid] = 0.f; csq[tid] = 0.f; }
    if (MODE == 2) {
        if (tid < HH) {
            float m = colsum[tid] * (1.f / NN);
            float v = colsq[tid] * (1.f / NN) - m * m;
            float a = bng[tid] * rsqrtf(v + BN_EPS);
            bsc[tid] = a;
            bsh[tid] = bnb[tid] - m * a;
        }
        __syncthreads();
    }

    int arow = r0 + wave * 16 + lrow;
    f32x4 acc[8];
#pragma unroll
    for (int c = 0; c < 8; c++) acc[c] = (f32x4){0.f, 0.f, 0.f, 0.f};

#pragma unroll
    for (int ks = 0; ks < 4; ks++) {
        int kb = ks * 32 + kgrp * 8;
        float av[8];
        if (arow < NN) {
            float4 p0 = *(const float4*)(A + (size_t)arow * HH + kb);
            float4 p1 = *(const float4*)(A + (size_t)arow * HH + kb + 4);
            av[0] = p0.x; av[1] = p0.y; av[2] = p0.z; av[3] = p0.w;
            av[4] = p1.x; av[5] = p1.y; av[6] = p1.z; av[7] = p1.w;
        } else {
#pragma unroll
            for (int j = 0; j < 8; j++) av[j] = 0.f;
        }
        if (MODE == 2) {
#pragma unroll
            for (int j = 0; j < 8; j++)
                av[j] = fmaxf(fmaf(av[j], bsc[kb + j], bsh[kb + j]), 0.f);
        }
        short8 ahi, alo;
#pragma unroll
        for (int j = 0; j < 8; j++) {
            unsigned short hb = bf16_rne(av[j]);
            ahi[j] = (short)hb;
            alo[j] = (short)bf16_rne(av[j] - bf16_to_f32(hb));
        }
#pragma unroll
        for (int c = 0; c < 8; c++) {
            size_t woff = (size_t)(c * 16 + lrow) * HH + kb;
            short8 whi = *(const short8*)(wt_hi + woff);
            short8 wlo = *(const short8*)(wt_lo + woff);
            acc[c] = __builtin_amdgcn_mfma_f32_16x16x32_bf16(ahi, whi, acc[c], 0, 0, 0);
            acc[c] = __builtin_amdgcn_mfma_f32_16x16x32_bf16(alo, whi, acc[c], 0, 0, 0);
            acc[c] = __builtin_amdgcn_mfma_f32_16x16x32_bf16(ahi, wlo, acc[c], 0, 0, 0);
        }
    }

    int row_l = tid >> 3, cg = tid & 7;   // epilogue mapping: 32 rows x 8 col-groups
    float ps[16], pq[16];
    if (MODE == 1) {
#pragma unroll
        for (int j = 0; j < 16; j++) { ps[j] = 0.f; pq[j] = 0.f; }
    }

#pragma unroll
    for (int p = 0; p < 2; p++) {
        __syncthreads();
        if ((wave >> 1) == p) {
            int sr = (wave & 1) * 16;
#pragma unroll
            for (int c = 0; c < 8; c++) {
                float bv = bias[c * 16 + lrow];
#pragma unroll
                for (int reg = 0; reg < 4; reg++)
                    cstage[sr + kgrp * 4 + reg][c * 16 + lrow] = acc[c][reg] + bv;
            }
        }
        __syncthreads();
        int r = r0 + p * 32 + row_l;
        float z[16];
#pragma unroll
        for (int j = 0; j < 4; j++) {
            float4 v = *(float4*)&cstage[row_l][j * 32 + cg * 4];
            z[j * 4 + 0] = v.x; z[j * 4 + 1] = v.y; z[j * 4 + 2] = v.z; z[j * 4 + 3] = v.w;
        }
        if (MODE == 0) {
            if (r < NN) {
#pragma unroll
                for (int j = 0; j < 4; j++) {
                    int col = j * 32 + cg * 4;
                    *(float4*)(Out + (size_t)r * HH + col) =
                        make_float4(z[j * 4], z[j * 4 + 1], z[j * 4 + 2], z[j * 4 + 3]);
                    uint2 pk;
                    pk.x = (unsigned)bf16_rne(z[j * 4]) | ((unsigned)bf16_rne(z[j * 4 + 1]) << 16);
                    pk.y = (unsigned)bf16_rne(z[j * 4 + 2]) | ((unsigned)bf16_rne(z[j * 4 + 3]) << 16);
                    *(uint2*)(hbf_out + (size_t)r * HH + col) = pk;
                }
            }
        } else if (MODE == 1) {
            if (r < NN) {
#pragma unroll
                for (int j = 0; j < 4; j++) {
                    int col = j * 32 + cg * 4;
                    *(float4*)(Out + (size_t)r * HH + col) =
                        make_float4(z[j * 4], z[j * 4 + 1], z[j * 4 + 2], z[j * 4 + 3]);
                }
#pragma unroll
                for (int j = 0; j < 16; j++) { ps[j] += z[j]; pq[j] += z[j] * z[j]; }
            }
        } else {
            if (r < NN) {
                float t[16];
                float s = 0.f, q = 0.f;
#pragma unroll
                for (int j = 0; j < 4; j++) {
                    int col = j * 32 + cg * 4;
                    float4 hv = *(const float4*)(Hbuf + (size_t)r * HH + col);
                    float h4[4] = {hv.x, hv.y, hv.z, hv.w};
#pragma unroll
                    for (int i = 0; i < 4; i++) {
                        float tv = h4[i] + fmaxf(z[j * 4 + i], 0.f);
                        t[j * 4 + i] = tv;
                        s += tv; q += tv * tv;
                    }
                }
                // 8 consecutive lanes own one row -> xor masks 1,2,4
#pragma unroll
                for (int m = 1; m < 8; m <<= 1) {
                    s += __shfl_xor(s, m);
                    q += __shfl_xor(q, m);
                }
                float mu = s * (1.f / 128.f);
                float var = q * (1.f / 128.f) - mu * mu;
                float rs = rsqrtf(var + LN_EPS);
#pragma unroll
                for (int j = 0; j < 4; j++) {
                    int col = j * 32 + cg * 4;
                    float4 g = *(const float4*)(lng + col);
                    float4 bb = *(const float4*)(lnb + col);
                    float o0 = (t[j * 4 + 0] - mu) * rs * g.x + bb.x;
                    float o1 = (t[j * 4 + 1] - mu) * rs * g.y + bb.y;
                    float o2 = (t[j * 4 + 2] - mu) * rs * g.z + bb.z;
                    float o3 = (t[j * 4 + 3] - mu) * rs * g.w + bb.w;
                    *(float4*)(Hbuf + (size_t)r * HH + col) = make_float4(o0, o1, o2, o3);
                    if (hbf_out) {
                        uint2 pk;
                        pk.x = (unsigned)bf16_rne(o0) | ((unsigned)bf16_rne(o1) << 16);
                        pk.y = (unsigned)bf16_rne(o2) | ((unsigned)bf16_rne(o3) << 16);
                        *(uint2*)(hbf_out + (size_t)r * HH + col) = pk;
                    }
                }
            }
        }
    }

    if (MODE == 1) {
        // lanes differing in bits 3..5 share cg -> reduce 8 rows of this wave
#pragma unroll
        for (int j = 0; j < 16; j++) {
            ps[j] += __shfl_xor(ps[j], 8);  pq[j] += __shfl_xor(pq[j], 8);
            ps[j] += __shfl_xor(ps[j], 16); pq[j] += __shfl_xor(pq[j], 16);
            ps[j] += __shfl_xor(ps[j], 32); pq[j] += __shfl_xor(pq[j], 32);
        }
        if (lane < 8) {
#pragma unroll
            for (int j = 0; j < 16; j++) {
                int col = (j >> 2) * 32 + lane * 4 + (j & 3);
                atomicAdd(&csum[col], ps[j]);
                atomicAdd(&csq[col], pq[j]);
            }
        }
        __syncthreads();
        if (tid < HH) {
            atomicAdd(&colsum[tid], csum[tid]);
            atomicAdd(&colsq[tid], csq[tid]);
        }
    }
}

// ---------------- pooling ----------------

__global__ void pool_kernel(const float* __restrict__ h, const int* __restrict__ batch,
                            float* __restrict__ psum, float* __restrict__ pcnt)
{
    int t = threadIdx.x;  // 128
    int n0 = blockIdx.x * POOL_CHUNK;
    int n1 = n0 + POOL_CHUNK; if (n1 > NN) n1 = NN;
    if (n0 >= NN) return;
    float acc = 0.f;
    int cur = batch[n0];
    int cnt = 0;
    for (int n = n0; n < n1; n++) {
        int g = batch[n];
        if (g != cur) {
            atomicAdd(&psum[cur * HH + t], acc);
            if (t == 0) atomicAdd(&pcnt[cur], (float)cnt);
            acc = 0.f; cnt = 0; cur = g;
        }
        acc += h[(size_t)n * HH + t];
        cnt++;
    }
    atomicAdd(&psum[cur * HH + t], acc);
    if (t == 0) atomicAdd(&pcnt[cur], (float)cnt);
}

__global__ void pool_final(const float* __restrict__ psum, const float* __restrict__ pcnt,
                           float* __restrict__ out)
{
    int i = blockIdx.x * blockDim.x + threadIdx.x;
    if (i < GG * HH) {
        float c = pcnt[i >> 7];
        out[i] = psum[i] / fmaxf(c, 1.f);
    }
}

// ---------------- launch ----------------

extern "C" void kernel_launch(void* const* d_in, const int* in_sizes, int n_in,
                              void* d_out, int out_size, void* d_ws, size_t ws_size,
                              hipStream_t stream)
{
    const float* x     = (const float*)d_in[0];
    const float* W0    = (const float*)d_in[1];
    const float* b0    = (const float*)d_in[2];
    const float* eps_l = (const float*)d_in[3];
    const float* W1    = (const float*)d_in[4];
    const float* b1    = (const float*)d_in[5];
    const float* bng   = (const float*)d_in[6];
    const float* bnb   = (const float*)d_in[7];
    const float* W2    = (const float*)d_in[8];
    const float* b2    = (const float*)d_in[9];
    const float* lng   = (const float*)d_in[10];
    const float* lnb   = (const float*)d_in[11];
    const int*   ei    = (const int*)d_in[12];
    const int*   batch = (const int*)d_in[13];
    float* out = (float*)d_out;

    char* ws = (char*)d_ws;
    size_t off = 0;
    auto alloc = [&](size_t bytes) -> void* {
        void* p = ws + off;
        off += (bytes + 255) & ~(size_t)255;
        return p;
    };
    float* hbuf   = (float*)alloc((size_t)NN * HH * 4);
    float* ubuf   = (float*)alloc((size_t)NN * HH * 4);   // u, then z1 in-place
    unsigned short* hbf = (unsigned short*)alloc((size_t)NN * HH * 2);
    int*   colidx = (int*)alloc((size_t)2 * EE * 4);
    int*   pairs  = (int*)alloc((size_t)2 * EE * 4);
    int*   rp     = (int*)alloc((size_t)(NN + 1) * 4);
    int*   bcnt   = (int*)alloc((NBUK + 1) * 4);
    int*   bbase  = (int*)alloc((NBUK + 1) * 4);
    int*   bcur   = (int*)alloc((NBUK + 1) * 4);
    float* colsum = (float*)alloc((size_t)LL * HH * 2 * 4);  // [l][sum|sq][HH]
    float* psum   = (float*)alloc((size_t)GG * HH * 4);
    float* pcnt   = (float*)alloc(GG * 4);
    short* wt_hi  = (short*)alloc((size_t)9 * HH * HH * 2);
    short* wt_lo  = (short*)alloc((size_t)9 * HH * HH * 2);

    hipMemsetAsync(bcnt, 0, (NBUK + 1) * 4, stream);
    hipMemsetAsync(colsum, 0, (size_t)LL * HH * 2 * 4, stream);
    hipMemsetAsync(psum, 0, (size_t)GG * HH * 4, stream);
    hipMemsetAsync(pcnt, 0, GG * 4, stream);

    prep_w<<<(9 * HH * HH + 255) / 256, 256, 0, stream>>>(W0, W1, W2, wt_hi, wt_lo);

    bucket_count<<<512, 256, 0, stream>>>(ei, bcnt);
    bucket_scan<<<1, 512, 0, stream>>>(bcnt, bbase, bcur, rp);
    bucket_scatter<<<(2 * EE + BCHUNK - 1) / BCHUNK, 256, 0, stream>>>(ei, bcur, pairs);
    bucket_build<<<NBUK, 256, 0, stream>>>(pairs, bbase, rp, colidx);

    int gb = (NN + 63) / 64;
    // encode: hbuf = x @ W0 + b0 (+ hbf mirror)
    gemm_v5<0><<<gb, 256, 0, stream>>>(x, wt_hi, wt_lo, b0, hbuf,
                                       nullptr, nullptr, nullptr, nullptr, nullptr, nullptr,
                                       nullptr, hbf);

    for (int l = 0; l < LL; l++) {
        float* cs = colsum + (size_t)l * HH * 2;
        float* cq = cs + HH;
        // u = (1+eps)h + sum_nb h  (gather from bf16 mirror)
        agg_kernel<<<(NN + 3) / 4, 256, 0, stream>>>((const unsigned*)hbf, rp, colidx, eps_l, l, ubuf);
        // z1 = u @ W1 + b1 (in-place in ubuf) + column stats
        gemm_v5<1><<<gb, 256, 0, stream>>>(ubuf, wt_hi + (size_t)(1 + l) * HH * HH,
                                           wt_lo + (size_t)(1 + l) * HH * HH, b1 + l * HH, ubuf,
                                           cs, cq, nullptr, nullptr, nullptr, nullptr,
                                           nullptr, nullptr);
        // h = LN(h + relu(relu(BN(z1)) @ W2 + b2)) (+ hbf mirror except last layer)
        gemm_v5<2><<<gb, 256, 0, stream>>>(ubuf, wt_hi + (size_t)(5 + l) * HH * HH,
                                           wt_lo + (size_t)(5 + l) * HH * HH, b2 + l * HH, nullptr,
                                           cs, cq, bng + l * HH, bnb + l * HH,
                                           lng + l * HH, lnb + l * HH, hbuf,
                                           (l == LL - 1) ? nullptr : hbf);
    }

    pool_kernel<<<(NN + POOL_CHUNK - 1) / POOL_CHUNK, 128, 0, stream>>>(hbuf, batch, psum, pcnt);
    pool_final<<<(GG * HH + 255) / 256, 256, 0, stream>>>(psum, pcnt, out);
}

// Round 6
// 924.973 us; speedup vs baseline: 1.4270x; 1.2998x over previous
//
#include <hip/hip_runtime.h>

#define NN 100000
#define EE 800000
#define HH 128
#define LL 4
#define GG 64
#define BN_EPS 1e-5f
#define LN_EPS 1e-5f
#define POOL_CHUNK 64
#define NBUK ((NN + 255) >> 8)   // 391 buckets of 256 rows
#define CAP 8192
#define BCHUNK 8192

typedef __attribute__((ext_vector_type(8))) short short8;
typedef __attribute__((ext_vector_type(4))) float f32x4;

__device__ inline unsigned short bf16_rne(float f) {
    unsigned u = __float_as_uint(f);
    return (unsigned short)((u + 0x7FFF + ((u >> 16) & 1)) >> 16);
}
__device__ inline float bf16_to_f32(unsigned short h) {
    return __uint_as_float((unsigned)h << 16);
}

// ---------------- CSR build: bucket sort (256 rows / bucket) ----------------

__global__ __launch_bounds__(256) void bucket_count(const int* __restrict__ ei, int* __restrict__ bcnt) {
    __shared__ int h[NBUK];
    int tid = threadIdx.x;
    for (int i = tid; i < NBUK; i += 256) h[i] = 0;
    __syncthreads();
    for (int e = blockIdx.x * 256 + tid; e < 2 * EE; e += gridDim.x * 256) {
        int r = ei[e];
        int c = (e < EE) ? ei[e + EE] : ei[e - EE];
        if (r != c) atomicAdd(&h[r >> 8], 1);
    }
    __syncthreads();
    for (int i = tid; i < NBUK; i += 256) if (h[i]) atomicAdd(&bcnt[i], h[i]);
}

__global__ void bucket_scan(const int* __restrict__ bcnt, int* __restrict__ bbase,
                            int* __restrict__ bcur, int* __restrict__ rp) {
    __shared__ int sh[512];
    int t = threadIdx.x;
    sh[t] = (t < NBUK) ? bcnt[t] : 0;
    __syncthreads();
    for (int off = 1; off < 512; off <<= 1) {
        int x = (t >= off) ? sh[t - off] : 0;
        __syncthreads();
        sh[t] += x;
        __syncthreads();
    }
    if (t < NBUK) {
        int excl = (t > 0) ? sh[t - 1] : 0;
        bbase[t] = excl;
        bcur[t] = excl;
    }
    if (t == NBUK - 1) {
        bbase[NBUK] = sh[t];
        rp[NN] = sh[t];
    }
}

__global__ __launch_bounds__(256) void bucket_scatter(const int* __restrict__ ei, int* __restrict__ bcur,
                                                      int* __restrict__ pairs) {
    __shared__ int h[NBUK];
    __shared__ int curb[NBUK];
    int tid = threadIdx.x;
    for (int i = tid; i < NBUK; i += 256) h[i] = 0;
    __syncthreads();
    int base = blockIdx.x * BCHUNK;
#pragma unroll 4
    for (int k = 0; k < BCHUNK / 256; k++) {
        int e = base + k * 256 + tid;
        if (e < 2 * EE) {
            int r = ei[e];
            int c = (e < EE) ? ei[e + EE] : ei[e - EE];
            if (r != c) atomicAdd(&h[r >> 8], 1);
        }
    }
    __syncthreads();
    for (int i = tid; i < NBUK; i += 256) {
        int n = h[i];
        curb[i] = n ? atomicAdd(&bcur[i], n) : 0;
    }
    __syncthreads();
#pragma unroll 4
    for (int k = 0; k < BCHUNK / 256; k++) {
        int e = base + k * 256 + tid;
        if (e < 2 * EE) {
            int r = ei[e];
            int c = (e < EE) ? ei[e + EE] : ei[e - EE];
            if (r != c) {
                int p = atomicAdd(&curb[r >> 8], 1);
                pairs[p] = ((r & 255) << 17) | c;
            }
        }
    }
}

__global__ __launch_bounds__(256) void bucket_build(const int* __restrict__ pairs, const int* __restrict__ bbase,
                                                    int* __restrict__ rp, int* __restrict__ colidx) {
    __shared__ int hist[256], off[256], lcol[CAP];
    int b = blockIdx.x, tid = threadIdx.x;
    int s = bbase[b];
    int size = bbase[b + 1] - s;
    hist[tid] = 0;
    __syncthreads();
    for (int i = tid; i < size; i += 256) atomicAdd(&hist[pairs[s + i] >> 17], 1);
    __syncthreads();
    off[tid] = hist[tid];
    __syncthreads();
    for (int o = 1; o < 256; o <<= 1) {
        int x = (tid >= o) ? off[tid - o] : 0;
        __syncthreads();
        off[tid] += x;
        __syncthreads();
    }
    int excl = (tid > 0) ? off[tid - 1] : 0;
    int r = (b << 8) + tid;
    if (r < NN) rp[r] = s + excl;
    hist[tid] = excl;
    __syncthreads();
    if (size <= CAP) {
        for (int i = tid; i < size; i += 256) {
            int u = pairs[s + i];
            int p = atomicAdd(&hist[u >> 17], 1);
            lcol[p] = u & 0x1FFFF;
        }
        __syncthreads();
        for (int i = tid; i < size; i += 256) colidx[s + i] = lcol[i];
    } else {
        for (int i = tid; i < size; i += 256) {
            int u = pairs[s + i];
            int p = atomicAdd(&hist[u >> 17], 1);
            colidx[s + p] = u & 0x1FFFF;
        }
    }
}

// ---------------- weight prep: transpose + split fp32 -> bf16 hi/lo, FRAGMENT ORDER ----------------
// fragment order: element (n,k) of W^T stored at (( (k>>3)*8 + (n>>4) )*128 + (n&15)*8 + (k&7))
// so that lane (lrow,kgrp) reading its 8-k fragment for col-tile c reads 16B at
// ((kblk*8 + c)*128 + lrow*8), consecutive across lrow -> conflict-free LDS & coalesced global.

__global__ void prep_w(const float* __restrict__ W0, const float* __restrict__ W1,
                       const float* __restrict__ W2,
                       short* __restrict__ wt_hi, short* __restrict__ wt_lo) {
    int i = blockIdx.x * 256 + threadIdx.x;
    if (i >= 9 * HH * HH) return;
    int mat = i >> 14, rem = i & 16383;
    int n = rem >> 7, k = rem & 127;
    const float* src = (mat == 0) ? W0 : ((mat <= 4) ? W1 + (size_t)(mat - 1) * HH * HH
                                                     : W2 + (size_t)(mat - 5) * HH * HH);
    float v = src[(size_t)k * HH + n];
    unsigned short h = bf16_rne(v);
    int off = (mat << 14) + (((k >> 3) * 8 + (n >> 4)) << 7) + ((n & 15) << 3) + (k & 7);
    wt_hi[off] = (short)h;
    wt_lo[off] = (short)bf16_rne(v - bf16_to_f32(h));
}

// ---------------- aggregation: u = (1+eps)*h + sum_nb h[nb], gather from bf16 mirror ----------------

__global__ __launch_bounds__(256) void agg_kernel(
    const unsigned int* __restrict__ hbf, const int* __restrict__ rp, const int* __restrict__ colidx,
    const float* __restrict__ eps_l, int layer, float* __restrict__ u)
{
    int node = blockIdx.x * 4 + (threadIdx.x >> 6);
    if (node >= NN) return;
    int lane = threadIdx.x & 63;
    float eps1 = 1.0f + eps_l[layer];
    unsigned sv = hbf[node * 64 + lane];
    float ax = __uint_as_float(sv << 16) * eps1;
    float ay = __uint_as_float(sv & 0xFFFF0000u) * eps1;
    int i = rp[node], end = rp[node + 1];
    for (; i + 4 <= end; i += 4) {
        unsigned v0 = hbf[colidx[i] * 64 + lane];
        unsigned v1 = hbf[colidx[i + 1] * 64 + lane];
        unsigned v2 = hbf[colidx[i + 2] * 64 + lane];
        unsigned v3 = hbf[colidx[i + 3] * 64 + lane];
        ax += __uint_as_float(v0 << 16) + __uint_as_float(v1 << 16)
            + __uint_as_float(v2 << 16) + __uint_as_float(v3 << 16);
        ay += __uint_as_float(v0 & 0xFFFF0000u) + __uint_as_float(v1 & 0xFFFF0000u)
            + __uint_as_float(v2 & 0xFFFF0000u) + __uint_as_float(v3 & 0xFFFF0000u);
    }
    for (; i < end; i++) {
        unsigned v = hbf[colidx[i] * 64 + lane];
        ax += __uint_as_float(v << 16);
        ay += __uint_as_float(v & 0xFFFF0000u);
    }
    ((float2*)(u + (size_t)node * HH))[lane] = make_float2(ax, ay);
}

// ---------------- GEMM v6: 64 rows/block (4 waves x 16 rows), W-hi in LDS, A fully prefetched ----
// MODE 0: Out = A@W + bias; + hbf mirror (LDS-staged, coalesced)
// MODE 1: Out = A@W + bias (in-place safe); column stats
// MODE 2: A' = relu(BN(A)); Hbuf = LN(Hbuf + relu(A'@W + bias)); + hbf mirror if non-null

template<int MODE>
__global__ __launch_bounds__(256, 4) void gemm_v6(
    const float* __restrict__ A,
    const short* __restrict__ wt_hi, const short* __restrict__ wt_lo,
    const float* __restrict__ bias,
    float* __restrict__ Out,
    float* __restrict__ colsum, float* __restrict__ colsq,
    const float* __restrict__ bng, const float* __restrict__ bnb,
    const float* __restrict__ lng, const float* __restrict__ lnb,
    float* __restrict__ Hbuf, unsigned short* __restrict__ hbf_out)
{
    __shared__ short wh[HH * HH];    // 32 KB W-hi (fragment order); reused as bf16 C-stage
    __shared__ float stats[2 * HH];  // mode1: csum|csq ; mode2: bsc|bsh
    int tid = threadIdx.x;
    int wave = tid >> 6, lane = tid & 63;
    int lrow = lane & 15, kgrp = lane >> 4;
    int r0 = blockIdx.x * 64;
    int arow = r0 + wave * 16 + lrow;

    // cooperative stage of W-hi: 2048 x 16B, linear -> coalesced + conflict-free
    {
        const short8* src = (const short8*)wt_hi;
        short8* dst = (short8*)wh;
#pragma unroll
        for (int i = 0; i < 8; i++) dst[tid + i * 256] = src[tid + i * 256];
    }
    if (MODE == 1) stats[tid] = 0.f;
    if (MODE == 2) {
        if (tid < HH) {
            float m = colsum[tid] * (1.f / NN);
            float v = colsq[tid] * (1.f / NN) - m * m;
            float a = bng[tid] * rsqrtf(v + BN_EPS);
            stats[tid] = a;
            stats[HH + tid] = bnb[tid] - m * a;
        }
    }

    // prefetch ALL A fragments (8 x float4 per lane)
    float4 a0[4], a1[4];
    if (arow < NN) {
#pragma unroll
        for (int ks = 0; ks < 4; ks++) {
            int kb = ks * 32 + kgrp * 8;
            a0[ks] = *(const float4*)(A + (size_t)arow * HH + kb);
            a1[ks] = *(const float4*)(A + (size_t)arow * HH + kb + 4);
        }
    } else {
#pragma unroll
        for (int ks = 0; ks < 4; ks++) {
            a0[ks] = make_float4(0.f, 0.f, 0.f, 0.f);
            a1[ks] = a0[ks];
        }
    }
    __syncthreads();

    f32x4 acc[8];
#pragma unroll
    for (int c = 0; c < 8; c++) acc[c] = (f32x4){0.f, 0.f, 0.f, 0.f};

#pragma unroll
    for (int ks = 0; ks < 4; ks++) {
        int kb = ks * 32 + kgrp * 8;
        float av[8] = {a0[ks].x, a0[ks].y, a0[ks].z, a0[ks].w,
                       a1[ks].x, a1[ks].y, a1[ks].z, a1[ks].w};
        if (MODE == 2) {
#pragma unroll
            for (int j = 0; j < 8; j++)
                av[j] = fmaxf(fmaf(av[j], stats[kb + j], stats[HH + kb + j]), 0.f);
        }
        short8 ahi, alo;
#pragma unroll
        for (int j = 0; j < 8; j++) {
            unsigned short hb = bf16_rne(av[j]);
            ahi[j] = (short)hb;
            alo[j] = (short)bf16_rne(av[j] - bf16_to_f32(hb));
        }
        int fb = (ks * 4 + kgrp) * 8;  // fragment-block row base
#pragma unroll
        for (int c = 0; c < 8; c++) {
            short8 whi = *(const short8*)(wh + ((fb + c) << 7) + (lrow << 3));
            short8 wlo = *(const short8*)(wt_lo + (size_t)((fb + c) << 7) + (lrow << 3));
            acc[c] = __builtin_amdgcn_mfma_f32_16x16x32_bf16(ahi, whi, acc[c], 0, 0, 0);
            acc[c] = __builtin_amdgcn_mfma_f32_16x16x32_bf16(alo, whi, acc[c], 0, 0, 0);
            acc[c] = __builtin_amdgcn_mfma_f32_16x16x32_bf16(ahi, wlo, acc[c], 0, 0, 0);
        }
    }

    // C layout: row = wave*16 + kgrp*4 + reg, col = c*16 + lrow
    float bv[8];
#pragma unroll
    for (int c = 0; c < 8; c++) bv[c] = bias[c * 16 + lrow];
    int lrb = wave * 16 + kgrp * 4;

    if (MODE == 0) {
        __syncthreads();  // all ds_reads of wh done
        unsigned short* hst = (unsigned short*)wh;
#pragma unroll
        for (int c = 0; c < 8; c++)
#pragma unroll
            for (int reg = 0; reg < 4; reg++) {
                float z = acc[c][reg] + bv[c];
                int r = r0 + lrb + reg;
                if (r < NN) Out[(size_t)r * HH + c * 16 + lrow] = z;
                hst[(lrb + reg) * HH + c * 16 + lrow] = bf16_rne(z);
            }
        __syncthreads();
        // coalesced bf16 mirror store: 64 rows x 128 ushort = 1024 uint4
#pragma unroll
        for (int i = 0; i < 4; i++) {
            int idx = tid + i * 256;
            int row = idx >> 4;
            int r = r0 + row;
            if (r < NN)
                *(uint4*)(hbf_out + (size_t)r * HH + (idx & 15) * 8) = ((const uint4*)wh)[idx];
        }
    } else if (MODE == 1) {
        float ps[8], pq[8];
#pragma unroll
        for (int c = 0; c < 8; c++) { ps[c] = 0.f; pq[c] = 0.f; }
#pragma unroll
        for (int c = 0; c < 8; c++)
#pragma unroll
            for (int reg = 0; reg < 4; reg++) {
                int r = r0 + lrb + reg;
                if (r < NN) {
                    float z = acc[c][reg] + bv[c];
                    Out[(size_t)r * HH + c * 16 + lrow] = z;
                    ps[c] += z; pq[c] += z * z;
                }
            }
#pragma unroll
        for (int c = 0; c < 8; c++) {
            ps[c] += __shfl_xor(ps[c], 16); pq[c] += __shfl_xor(pq[c], 16);
            ps[c] += __shfl_xor(ps[c], 32); pq[c] += __shfl_xor(pq[c], 32);
        }
        if (kgrp == 0) {
#pragma unroll
            for (int c = 0; c < 8; c++) {
                atomicAdd(&stats[c * 16 + lrow], ps[c]);
                atomicAdd(&stats[HH + c * 16 + lrow], pq[c]);
            }
        }
        __syncthreads();
        if (tid < HH) {
            atomicAdd(&colsum[tid], stats[tid]);
            atomicAdd(&colsq[tid], stats[HH + tid]);
        }
    } else {
        float lg[8], lb[8];
#pragma unroll
        for (int c = 0; c < 8; c++) {
            lg[c] = lng[c * 16 + lrow];
            lb[c] = lnb[c * 16 + lrow];
        }
        __syncthreads();  // wh reads done; safe to reuse as staging
        unsigned short* hst = (unsigned short*)wh;
#pragma unroll
        for (int reg = 0; reg < 4; reg++) {
            int r = r0 + lrb + reg;
            if (r < NN) {   // uniform across each 16-lane group
                float tv[8];
                float s = 0.f, q = 0.f;
#pragma unroll
                for (int c = 0; c < 8; c++) {
                    float hold = Hbuf[(size_t)r * HH + c * 16 + lrow];
                    tv[c] = hold + fmaxf(acc[c][reg] + bv[c], 0.f);
                    s += tv[c]; q += tv[c] * tv[c];
                }
#pragma unroll
                for (int m = 1; m < 16; m <<= 1) {
                    s += __shfl_xor(s, m);
                    q += __shfl_xor(q, m);
                }
                float mu = s * (1.f / 128.f);
                float var = q * (1.f / 128.f) - mu * mu;
                float rs = rsqrtf(var + LN_EPS);
#pragma unroll
                for (int c = 0; c < 8; c++) {
                    float o = (tv[c] - mu) * rs * lg[c] + lb[c];
                    Hbuf[(size_t)r * HH + c * 16 + lrow] = o;
                    if (hbf_out) hst[(lrb + reg) * HH + c * 16 + lrow] = bf16_rne(o);
                }
            }
        }
        if (hbf_out) {
            __syncthreads();
#pragma unroll
            for (int i = 0; i < 4; i++) {
                int idx = tid + i * 256;
                int row = idx >> 4;
                int r = r0 + row;
                if (r < NN)
                    *(uint4*)(hbf_out + (size_t)r * HH + (idx & 15) * 8) = ((const uint4*)wh)[idx];
            }
        }
    }
}

// ---------------- pooling ----------------

__global__ void pool_kernel(const float* __restrict__ h, const int* __restrict__ batch,
                            float* __restrict__ psum, float* __restrict__ pcnt)
{
    int t = threadIdx.x;  // 128
    int n0 = blockIdx.x * POOL_CHUNK;
    int n1 = n0 + POOL_CHUNK; if (n1 > NN) n1 = NN;
    if (n0 >= NN) return;
    float acc = 0.f;
    int cur = batch[n0];
    int cnt = 0;
    for (int n = n0; n < n1; n++) {
        int g = batch[n];
        if (g != cur) {
            atomicAdd(&psum[cur * HH + t], acc);
            if (t == 0) atomicAdd(&pcnt[cur], (float)cnt);
            acc = 0.f; cnt = 0; cur = g;
        }
        acc += h[(size_t)n * HH + t];
        cnt++;
    }
    atomicAdd(&psum[cur * HH + t], acc);
    if (t == 0) atomicAdd(&pcnt[cur], (float)cnt);
}

__global__ void pool_final(const float* __restrict__ psum, const float* __restrict__ pcnt,
                           float* __restrict__ out)
{
    int i = blockIdx.x * blockDim.x + threadIdx.x;
    if (i < GG * HH) {
        float c = pcnt[i >> 7];
        out[i] = psum[i] / fmaxf(c, 1.f);
    }
}

// ---------------- launch ----------------

extern "C" void kernel_launch(void* const* d_in, const int* in_sizes, int n_in,
                              void* d_out, int out_size, void* d_ws, size_t ws_size,
                              hipStream_t stream)
{
    const float* x     = (const float*)d_in[0];
    const float* W0    = (const float*)d_in[1];
    const float* b0    = (const float*)d_in[2];
    const float* eps_l = (const float*)d_in[3];
    const float* W1    = (const float*)d_in[4];
    const float* b1    = (const float*)d_in[5];
    const float* bng   = (const float*)d_in[6];
    const float* bnb   = (const float*)d_in[7];
    const float* W2    = (const float*)d_in[8];
    const float* b2    = (const float*)d_in[9];
    const float* lng   = (const float*)d_in[10];
    const float* lnb   = (const float*)d_in[11];
    const int*   ei    = (const int*)d_in[12];
    const int*   batch = (const int*)d_in[13];
    float* out = (float*)d_out;

    char* ws = (char*)d_ws;
    size_t off = 0;
    auto alloc = [&](size_t bytes) -> void* {
        void* p = ws + off;
        off += (bytes + 255) & ~(size_t)255;
        return p;
    };
    float* hbuf   = (float*)alloc((size_t)NN * HH * 4);
    float* ubuf   = (float*)alloc((size_t)NN * HH * 4);   // u, then z1 in-place
    unsigned short* hbf = (unsigned short*)alloc((size_t)NN * HH * 2);
    int*   colidx = (int*)alloc((size_t)2 * EE * 4);
    int*   pairs  = (int*)alloc((size_t)2 * EE * 4);
    int*   rp     = (int*)alloc((size_t)(NN + 1) * 4);
    int*   bcnt   = (int*)alloc((NBUK + 1) * 4);
    int*   bbase  = (int*)alloc((NBUK + 1) * 4);
    int*   bcur   = (int*)alloc((NBUK + 1) * 4);
    float* colsum = (float*)alloc((size_t)LL * HH * 2 * 4);  // [l][sum|sq][HH]
    float* psum   = (float*)alloc((size_t)GG * HH * 4);
    float* pcnt   = (float*)alloc(GG * 4);
    short* wt_hi  = (short*)alloc((size_t)9 * HH * HH * 2);
    short* wt_lo  = (short*)alloc((size_t)9 * HH * HH * 2);

    hipMemsetAsync(bcnt, 0, (NBUK + 1) * 4, stream);
    hipMemsetAsync(colsum, 0, (size_t)LL * HH * 2 * 4, stream);
    hipMemsetAsync(psum, 0, (size_t)GG * HH * 4, stream);
    hipMemsetAsync(pcnt, 0, GG * 4, stream);

    prep_w<<<(9 * HH * HH + 255) / 256, 256, 0, stream>>>(W0, W1, W2, wt_hi, wt_lo);

    bucket_count<<<512, 256, 0, stream>>>(ei, bcnt);
    bucket_scan<<<1, 512, 0, stream>>>(bcnt, bbase, bcur, rp);
    bucket_scatter<<<(2 * EE + BCHUNK - 1) / BCHUNK, 256, 0, stream>>>(ei, bcur, pairs);
    bucket_build<<<NBUK, 256, 0, stream>>>(pairs, bbase, rp, colidx);

    int gb = (NN + 63) / 64;
    // encode: hbuf = x @ W0 + b0 (+ hbf mirror)
    gemm_v6<0><<<gb, 256, 0, stream>>>(x, wt_hi, wt_lo, b0, hbuf,
                                       nullptr, nullptr, nullptr, nullptr, nullptr, nullptr,
                                       nullptr, hbf);

    for (int l = 0; l < LL; l++) {
        float* cs = colsum + (size_t)l * HH * 2;
        float* cq = cs + HH;
        // u = (1+eps)h + sum_nb h  (gather from bf16 mirror)
        agg_kernel<<<(NN + 3) / 4, 256, 0, stream>>>((const unsigned*)hbf, rp, colidx, eps_l, l, ubuf);
        // z1 = u @ W1 + b1 (in-place in ubuf) + column stats
        gemm_v6<1><<<gb, 256, 0, stream>>>(ubuf, wt_hi + (size_t)(1 + l) * HH * HH,
                                           wt_lo + (size_t)(1 + l) * HH * HH, b1 + l * HH, ubuf,
                                           cs, cq, nullptr, nullptr, nullptr, nullptr,
                                           nullptr, nullptr);
        // h = LN(h + relu(relu(BN(z1)) @ W2 + b2)) (+ hbf mirror except last layer)
        gemm_v6<2><<<gb, 256, 0, stream>>>(ubuf, wt_hi + (size_t)(5 + l) * HH * HH,
                                           wt_lo + (size_t)(5 + l) * HH * HH, b2 + l * HH, nullptr,
                                           cs, cq, bng + l * HH, bnb + l * HH,
                                           lng + l * HH, lnb + l * HH, hbuf,
                                           (l == LL - 1) ? nullptr : hbf);
    }

    pool_kernel<<<(NN + POOL_CHUNK - 1) / POOL_CHUNK, 128, 0, stream>>>(hbuf, batch, psum, pcnt);
    pool_final<<<(GG * HH + 255) / 256, 256, 0, stream>>>(psum, pcnt, out);
}